// Round 10
// baseline (197.865 us; speedup 1.0000x reference)
//
#include <hip/hip_runtime.h>
#include <hip/hip_bf16.h>

typedef short bf16x8 __attribute__((ext_vector_type(8)));
typedef float f32x4 __attribute__((ext_vector_type(4)));

static constexpr int M_DIM = 16384;
static constexpr int N_DIM = 4096;
static constexpr int K_DIM = 1024;

static constexpr int CVT_BLOCKS = (M_DIM * K_DIM / 8) / 256;   // 8192
static constexpr int WT_BLOCKS  = N_DIM;                       // 4096 (R7 proven)

__device__ __forceinline__ unsigned short f2bf(float f) {
  union { float f; unsigned u; } v; v.f = f;
  unsigned r = v.u + 0x7FFFu + ((v.u >> 16) & 1u);
  return (unsigned short)(r >> 16);
}

// R7-proven fused prep: cvt blocks vectorized; one block per w^T column.
__global__ __launch_bounds__(256) void prep_kernel(
    const float* __restrict__ x, const float* __restrict__ a,
    const float* __restrict__ b, const float* __restrict__ s,
    unsigned short* __restrict__ xb, unsigned short* __restrict__ wT) {
  __shared__ float as_eff[8][64];
  __shared__ float bl[8][16];
  const int tid = threadIdx.x;

  if (blockIdx.x < CVT_BLOCKS) {
    const int i = (blockIdx.x * 256 + tid) * 2;
    float4 v0 = reinterpret_cast<const float4*>(x)[i];
    float4 v1 = reinterpret_cast<const float4*>(x)[i + 1];
    ushort4 o0, o1;
    o0.x = f2bf(v0.x); o0.y = f2bf(v0.y); o0.z = f2bf(v0.z); o0.w = f2bf(v0.w);
    o1.x = f2bf(v1.x); o1.y = f2bf(v1.y); o1.z = f2bf(v1.z); o1.w = f2bf(v1.w);
    reinterpret_cast<ushort4*>(xb)[i] = o0;
    reinterpret_cast<ushort4*>(xb)[i + 1] = o1;
    return;
  }

  const int n = blockIdx.x - CVT_BLOCKS;
  const int j = n >> 5, l = n & 31;

#pragma unroll
  for (int t = tid; t < 512; t += 256) {
    const int r = t >> 6, i = t & 63;
    as_eff[r][i] = a[(r * 64 + i) * 128 + j] * s[i * 128 + j];
  }
  if (tid < 128) {
    const int r = tid >> 4, kk = tid & 15;
    bl[r][kk] = b[(r * 16 + kk) * 32 + l];
  }
  __syncthreads();

  const int i = tid >> 2;
  const int kk0 = (tid & 3) * 4;
  float o[4] = {0.f, 0.f, 0.f, 0.f};
#pragma unroll
  for (int r = 0; r < 8; ++r) {
    const float av = as_eff[r][i];
#pragma unroll
    for (int q = 0; q < 4; ++q)
      o[q] += av * bl[r][kk0 + q];
  }
  ushort4 w4;
  w4.x = f2bf(o[0]); w4.y = f2bf(o[1]); w4.z = f2bf(o[2]); w4.w = f2bf(o[3]);
  *reinterpret_cast<ushort4*>(&wT[(size_t)n * K_DIM + tid * 4]) = w4;
}

// ---- 256x128 GEMM, BK=32, 256 threads, 48 KB LDS -> 2 blocks/CU resident ----
// C(M,N) = A(M,K) * BT(N,K)^T + bias ; A,BT bf16, C f32.
// 4 waves (2M x 2N); per wave: 128x64 out = 8x4 frags of 16x16x32 (acc[8][4]).
// Why: R6/R8/R9 proved the K-loop schedule is NOT the limiter (154 us invariant);
// at 1 block/CU the 4 serial blocks/CU expose prologue+epilogue (~50 us). Two
// co-resident blocks overlap one block's ends with the other's K-loop.
// Swizzle (64B rows, 4 chunks): LDS chunk p holds global chunk p^((row>>1)&3);
// read addr = row*64 + ((kg^((frow>>1)&3))<<4) -> 8 start-banks x 2 lanes, free.
// Vmcnt ledger: STGA=4, STGB=2 per tile. Publish queue =
// [B(t+1):2][A(t+1):4][B(t+2):2] -> vmcnt(2); t=30 -> vmcnt(0); t=31 none.
// lgkm: issue aF0-3(4),b01(2),[STGA],aF4-7(4),b23(2): WAITL(6)->m0-3xn01;
// WAITL(2)->m4-7xn01; WAITL(0)->midBAR->STGB->m0-7xn23 (reg-only)->publish.

#define PH_BARRIER __builtin_amdgcn_s_barrier()
#define SCHED0     __builtin_amdgcn_sched_barrier(0)
#define WAITV(N)   do { asm volatile("s_waitcnt vmcnt(" #N ")" ::: "memory"); SCHED0; } while (0)
#define WAITL(N)   do { asm volatile("s_waitcnt lgkmcnt(" #N ")" ::: "memory"); SCHED0; } while (0)

__global__ __launch_bounds__(256, 2) void gemm_kernel(
    const unsigned short* __restrict__ A, const unsigned short* __restrict__ BT,
    const float* __restrict__ bias, float* __restrict__ C) {
  __shared__ __align__(16) unsigned short Al[2][8192];   // 256 x 32 each
  __shared__ __align__(16) unsigned short Bl[2][4096];   // 128 x 32 each

  const int tid  = threadIdx.x;
  const int lane = tid & 63;
  const int wave = tid >> 6;          // 0..3
  const int wm = wave >> 1;           // 0..1
  const int wn = wave & 1;            // 0..1
  const int wr = wm * 128;
  const int wc = wn * 64;
  const int frow = lane & 15;
  const int kg = lane >> 4;           // 0..3
  const int swz = (kg ^ ((frow >> 1) & 3)) << 4;   // byte offset of 16B chunk in 64B row

  // grid: 2048 blocks = 64(M) x 32(N); 4x4 super-tiles -> 128 groups, XCD-bijective
  int bid = blockIdx.x;
  int g = bid >> 4, lid = bid & 15;
  g = ((g & 7) << 4) | (g >> 3);                 // 128 % 8 == 0, bijective
  const int bm = (g >> 3) * 4 + (lid >> 2);      // 0..63
  const int bn = (g & 7) * 4 + (lid & 3);        // 0..31
  const int brow = bm * 256, bcol = bn * 128;

  const unsigned short* Abase = A + (size_t)brow * K_DIM;
  const unsigned short* Bbase = BT + (size_t)bcol * K_DIM;

  // staging: one STG line = 4 waves x 1KB = 4KB = 64 rows x 64B.
  // thread t: row q*64 + (t>>2), src chunk (t&3)^((t>>3)&3) (pre-swizzled).
  const int srow = tid >> 2;                            // 0..63
  const int schunk = ((tid & 3) ^ ((tid >> 3) & 3)) * 8; // shorts
  const int ldsu = __builtin_amdgcn_readfirstlane(wave * 512);   // shorts

#define STG(dst, base, q, k0) __builtin_amdgcn_global_load_lds( \
    (const __attribute__((address_space(1))) void*)((base) + (size_t)((q)*64 + srow) * K_DIM + (k0) + schunk), \
    (__attribute__((address_space(3))) void*)((dst) + (q)*2048 + ldsu), 16, 0, 0)

#define STGA(dst, k0) do { STG(dst, Abase, 0, k0); STG(dst, Abase, 1, k0); \
                           STG(dst, Abase, 2, k0); STG(dst, Abase, 3, k0); } while (0)
#define STGB(dst, k0) do { STG(dst, Bbase, 0, k0); STG(dst, Bbase, 1, k0); } while (0)

#define LDA4(P, h) { _Pragma("unroll") for (int mi = 0; mi < 4; ++mi) \
    aF[(h)*4 + mi] = *(const bf16x8*)((const char*)(P) + (wr + ((h)*4 + mi) * 16 + frow) * 64 + swz); }
#define LDB2(P, h) { _Pragma("unroll") for (int ni = 0; ni < 2; ++ni) \
    bF[(h)*2 + ni] = *(const bf16x8*)((const char*)(P) + (wc + ((h)*2 + ni) * 16 + frow) * 64 + swz); }

#define MFMA_C(mlo, mcnt, nlo, ncnt) do { __builtin_amdgcn_s_setprio(1); \
    _Pragma("unroll") for (int mi = 0; mi < (mcnt); ++mi) \
    _Pragma("unroll") for (int ni = 0; ni < (ncnt); ++ni) \
      acc[(mlo)+mi][(nlo)+ni] = __builtin_amdgcn_mfma_f32_16x16x32_bf16( \
          aF[(mlo)+mi], bF[(nlo)+ni], acc[(mlo)+mi][(nlo)+ni], 0, 0, 0); \
    __builtin_amdgcn_s_setprio(0); } while (0)

  f32x4 acc[8][4] = {};
  bf16x8 aF[8], bF[4];

  // prologue: B0 -> Bl[0] (2), A0 -> Al[0] (4), B1 -> Bl[1] (2); leave B1 in flight
  STGB(Bl[0], 0);
  STGA(Al[0], 0);
  STGB(Bl[1], 32);
  WAITV(2);
  PH_BARRIER;

  unsigned short* a_rd = &Al[0][0]; unsigned short* a_st = &Al[1][0];
  unsigned short* b_rd = &Bl[0][0]; unsigned short* b_ot = &Bl[1][0];

#pragma unroll 1
  for (int t = 0; t < 32; ++t) {
    const int k = t * 32;
    LDA4(a_rd, 0); SCHED0;
    LDB2(b_rd, 0); SCHED0;
    if (t < 31) STGA(a_st, k + 32);               // A(t+1) -> other A buf
    LDA4(a_rd, 1); SCHED0;
    LDB2(b_rd, 1); SCHED0;
    WAITL(6);                                     // aF0-3, bF0-1 landed
    MFMA_C(0, 4, 0, 2);
    WAITL(2);                                     // aF4-7 landed
    MFMA_C(4, 4, 0, 2);
    WAITL(0);                                     // bF2-3 landed; all reads done
    PH_BARRIER;                                   // block-wide: b_rd reads drained
    if (t < 30) STGB(b_rd, k + 64);               // B(t+2) -> same phys buf as t reads
    MFMA_C(0, 8, 2, 2);                           // reg-only
    if (t < 30) { WAITV(2); } else if (t == 30) { WAITV(0); }
    PH_BARRIER;
    unsigned short* tp = a_rd; a_rd = a_st; a_st = tp;
    tp = b_rd; b_rd = b_ot; b_ot = tp;
  }

  // ---- epilogue: per-wave LDS transpose -> contiguous float4 stores ----
  __syncthreads();
  float* T = (float*)&Al[0][0];                   // 4 waves * 16*68 floats = 17.4 KB
  float* Tw = T + wave * (16 * 68);
  const int col4 = lane & 15;
  const int rsel = lane >> 4;
  float4 bv = *(const float4*)&bias[bcol + wc + col4 * 4];

#pragma unroll
  for (int mi = 0; mi < 8; ++mi) {
#pragma unroll
    for (int ni = 0; ni < 4; ++ni)
#pragma unroll
      for (int r = 0; r < 4; ++r)
        Tw[(kg * 4 + r) * 68 + ni * 16 + frow] = acc[mi][ni][r];
    WAITL(0);                                     // fence write->read
#pragma unroll
    for (int rr = 0; rr < 4; ++rr) {
      float4 v = *(float4*)&Tw[(rr * 4 + rsel) * 68 + col4 * 4];
      v.x += bv.x; v.y += bv.y; v.z += bv.z; v.w += bv.w;
      *(float4*)&C[(size_t)(brow + wr + mi * 16 + rr * 4 + rsel) * N_DIM + bcol + wc + col4 * 4] = v;
    }
    WAITL(0);                                     // reads done before next overwrite
  }
}

extern "C" void kernel_launch(void* const* d_in, const int* in_sizes, int n_in,
                              void* d_out, int out_size, void* d_ws, size_t ws_size,
                              hipStream_t stream) {
  const float* x    = (const float*)d_in[0];
  const float* a    = (const float*)d_in[1];
  const float* b    = (const float*)d_in[2];
  const float* s    = (const float*)d_in[3];
  const float* bias = (const float*)d_in[4];
  float* out = (float*)d_out;

  unsigned short* xb = (unsigned short*)d_ws;
  unsigned short* wT = (unsigned short*)((char*)d_ws + (size_t)M_DIM * K_DIM * 2);

  prep_kernel<<<CVT_BLOCKS + WT_BLOCKS, 256, 0, stream>>>(x, a, b, s, xb, wT);
  gemm_kernel<<<(M_DIM / 256) * (N_DIM / 128), 256, 0, stream>>>(xb, wT, bias, out);
}